// Round 1
// baseline (474.342 us; speedup 1.0000x reference)
//
#include <hip/hip_runtime.h>
#include <math.h>

// DTW 2048x2048, squared-difference cost, output sqrt(DTW[N-1][N-1]).
//
// Design: single workgroup (16 waves, 1024 threads) on one CU.
// Wave w owns rows [128w, 128w+128); lane l owns rows i0=128w+2l, i1=i0+1.
// Skewed pipeline: at wave-local step tau, lane l computes column j = tau - l
// for both its rows. 'up'/'diag' for row i0 come from lane l-1's bottom-row
// value via __shfl_up (lane l-1 computed column j at step tau-1).
// Wave boundaries (bottom row of each strip) pass through an LDS ring buffer.
// Waves are skewed by DSKEW=128 steps; a __syncthreads every CSTEP=64 steps
// makes producer writes (at global step g-65, always a previous epoch) visible
// before consumer reads -- no flags, no atomics, deterministic.

#define NLEN 2048
#define NW   16      // waves
#define CSTEP 64     // steps between barriers
#define DSKEW 128    // inter-wave skew in steps (>= CSTEP + 63)
#define RB   256     // ring columns per wave boundary (>= ~192 needed)
#define INFV 1e30f

__global__ __launch_bounds__(1024) void dtw_kernel(const float* __restrict__ X,
                                                   const float* __restrict__ Y,
                                                   float* __restrict__ out) {
    __shared__ float yS[NLEN];
    __shared__ float ring[(NW - 1) * RB];

    const int tid  = threadIdx.x;
    const int w    = tid >> 6;
    const int lane = tid & 63;

    // Stage y into LDS.
    yS[tid]        = Y[tid];
    yS[tid + 1024] = Y[tid + 1024];
    __syncthreads();

    const int   i0 = w * 128 + lane * 2;
    const float x0 = X[i0];
    const float x1 = X[i0 + 1];

    float v0 = INFV;     // DTW[i0][j_prev]  (left for row i0)
    float v1 = INFV;     // DTW[i1][j_prev]  (left for row i1)
    float uprev = INFV;  // DTW[i0-1][j_prev] (diag for row i0)

    // Total global steps: last wave (w=15) finishes at 15*128 + 2047 + 63.
    const int G = ((NW - 1) * DSKEW + NLEN + 63 + CSTEP - 1) / CSTEP * CSTEP; // 4032

    for (int gb = 0; gb < G; gb += CSTEP) {
        const int tau0 = gb - w * DSKEW;

        if (tau0 >= 64 && tau0 + CSTEP <= NLEN) {
            // ---- steady state: every lane active, no bounds checks ----
            #pragma unroll 4
            for (int s = 0; s < CSTEP; ++s) {
                const int j = tau0 + s - lane;
                float u_shfl = __shfl_up(v1, 1);
                float u_r    = (w == 0) ? INFV : ring[(w - 1) * RB + (j & (RB - 1))];
                float u      = (lane == 0) ? u_r : u_shfl;
                float yj = yS[j];
                float d0 = x0 - yj;
                float nv0 = fmaf(d0, d0, fminf(fminf(u, v0), uprev));
                float d1 = x1 - yj;
                float nv1 = fmaf(d1, d1, fminf(fminf(nv0, v1), v0));
                uprev = u; v0 = nv0; v1 = nv1;
                if (lane == 63 && w < NW - 1) ring[w * RB + (j & (RB - 1))] = nv1;
            }
        } else if (tau0 + CSTEP > 0 && tau0 < NLEN + 64) {
            // ---- ramp-up / ramp-down: per-lane activity guard ----
            for (int s = 0; s < CSTEP; ++s) {
                const int j = tau0 + s - lane;
                float u_shfl = __shfl_up(v1, 1);
                float u_r;
                if (w == 0) u_r = (j == 0) ? 0.0f : INFV;
                else        u_r = ring[(w - 1) * RB + (j & (RB - 1))];
                float u = (lane == 0) ? u_r : u_shfl;
                float yj = yS[j & (NLEN - 1)];
                float d0 = x0 - yj;
                float nv0 = fmaf(d0, d0, fminf(fminf(u, v0), uprev));
                float d1 = x1 - yj;
                float nv1 = fmaf(d1, d1, fminf(fminf(nv0, v1), v0));
                if (j >= 0 && j < NLEN) {
                    uprev = u; v0 = nv0; v1 = nv1;
                    if (lane == 63) {
                        if (w < NW - 1)      ring[w * RB + (j & (RB - 1))] = nv1;
                        else if (j == NLEN - 1) out[0] = sqrtf(nv1);
                    }
                }
            }
        }
        __syncthreads();
    }
}

extern "C" void kernel_launch(void* const* d_in, const int* in_sizes, int n_in,
                              void* d_out, int out_size, void* d_ws, size_t ws_size,
                              hipStream_t stream) {
    const float* x = (const float*)d_in[0];
    const float* y = (const float*)d_in[1];
    float* out = (float*)d_out;
    (void)in_sizes; (void)n_in; (void)out_size; (void)d_ws; (void)ws_size;
    dtw_kernel<<<1, 1024, 0, stream>>>(x, y, out);
}

// Round 2
// 274.637 us; speedup vs baseline: 1.7272x; 1.7272x over previous
//
#include <hip/hip_runtime.h>
#include <math.h>

// DTW 2048x2048, squared-diff cost, out = sqrt(DTW[2047][2047]).
//
// R=8 rows/lane, 4 waves (256 thr) on one CU, 1 wave/SIMD.
// Lane l of wave w owns rows 8*(64w+l) .. +7. At wave-local step tau, lane l
// computes column j = tau - l for its 8 rows (serial min+fma chain).
// Lane-to-lane "up"/"diag" flow: DPP wave_shr:1 of v[7]; lane 0 gets the
// ring value (row above the strip) injected via the DPP 'old' operand.
// Ring: unwrapped rows of 2240 slots (slot = col + 64). ALL lanes store
// v[7] each step; lane 63 (true strip boundary) writes each column last,
// so the consumer (skewed 128 steps behind, barrier every 64 steps) always
// reads lane-63 data. Virtual row -1 is all-INF; the DP seed enters as
// uprev=0 for tid 0 only (fixes the round-1 seed-leak bug).

#define NLEN  2048
#define NW    4
#define CSTEP 64
#define DSKEW 128
#define RROW  2240
#define GTOT  ((NW - 1) * DSKEW + NLEN + CSTEP)   // 2496
#define INFV  1e30f

__device__ __forceinline__ float dpp_shr1(float v, float inj) {
    int r = __builtin_amdgcn_update_dpp(
        __builtin_bit_cast(int, inj), __builtin_bit_cast(int, v),
        0x138 /*wave_shr:1*/, 0xF, 0xF, false /*bound_ctrl: keep old*/);
    return __builtin_bit_cast(float, r);
}

__global__ __launch_bounds__(256) void dtw_kernel(const float* __restrict__ X,
                                                  const float* __restrict__ Y,
                                                  float* __restrict__ out) {
    __shared__ __align__(16) float yS[NLEN];
    __shared__ float ring[(NW + 1) * RROW];   // row 0 = virtual row -1 (INF)

    const int tid  = threadIdx.x;
    const int w    = tid >> 6;
    const int lane = tid & 63;

    // Stage y (vectorized) and init virtual row -1.
    {
        const float4* Y4 = (const float4*)Y;
        float4* y4 = (float4*)yS;
        y4[tid]       = Y4[tid];
        y4[tid + 256] = Y4[tid + 256];
    }
    for (int k = tid; k < RROW; k += 256) ring[k] = INFV;
    __syncthreads();

    // Per-lane x values (rows tid*8 .. tid*8+7).
    float xr[8];
    {
        const float4 xa = *(const float4*)&X[tid * 8];
        const float4 xb = *(const float4*)&X[tid * 8 + 4];
        xr[0] = xa.x; xr[1] = xa.y; xr[2] = xa.z; xr[3] = xa.w;
        xr[4] = xb.x; xr[5] = xb.y; xr[6] = xb.z; xr[7] = xb.w;
    }

    float v[8];
    #pragma unroll
    for (int r = 0; r < 8; ++r) v[r] = INFV;
    // Seed: diag of cell (0,0) is DTW[-1][-1] = 0 (tid 0 only).
    float uprev = (tid == 0) ? 0.0f : INFV;

    const float* ringR = &ring[w * RROW + 64];        // read row above strip
    float*       ringW = &ring[(w + 1) * RROW + 64];  // write own bottom row

    for (int gb = 0; gb < GTOT; gb += CSTEP) {
        const int tau0 = gb - w * DSKEW;

        if (tau0 >= CSTEP && tau0 + CSTEP <= NLEN) {
            // ---- steady state: all cols in [1, 2047], no seeds, no guards ----
            const float* yp = &yS[tau0 - lane];
            const float* rp = &ringR[tau0];
            float*       wp = &ringW[tau0 - lane];
            #pragma unroll
            for (int s = 0; s < CSTEP; ++s) {
                float u_r = rp[s];              // uniform; used by lane 0 only
                float yj  = yp[s];
                float u   = dpp_shr1(v[7], u_r);
                float nv[8];
                #pragma unroll
                for (int r = 0; r < 8; ++r) {
                    float above = (r == 0) ? u : nv[r - 1];
                    float diag  = (r == 0) ? uprev : v[r - 1];
                    float m = fminf(fminf(v[r], diag), above);
                    float d = xr[r] - yj;
                    nv[r] = fmaf(d, d, m);
                }
                wp[s] = nv[7];
                uprev = u;
                #pragma unroll
                for (int r = 0; r < 8; ++r) v[r] = nv[r];
            }
        } else if (tau0 >= 0 && tau0 < NLEN + CSTEP) {
            // ---- ramp up/down: per-lane activity guard ----
            for (int s = 0; s < CSTEP; ++s) {
                const int j = tau0 + s - lane;
                float u_r = ringR[tau0 + s];
                float yj  = yS[j & (NLEN - 1)];
                float u   = dpp_shr1(v[7], u_r);
                float nv[8];
                #pragma unroll
                for (int r = 0; r < 8; ++r) {
                    float above = (r == 0) ? u : nv[r - 1];
                    float diag  = (r == 0) ? uprev : v[r - 1];
                    float m = fminf(fminf(v[r], diag), above);
                    float d = xr[r] - yj;
                    nv[r] = fmaf(d, d, m);
                }
                if (j >= 0 && j < NLEN) {
                    ringW[j] = nv[7];
                    uprev = u;
                    #pragma unroll
                    for (int r = 0; r < 8; ++r) v[r] = nv[r];
                    if (w == NW - 1 && lane == 63 && j == NLEN - 1)
                        out[0] = sqrtf(nv[7]);
                }
            }
        }
        __syncthreads();
    }
}

extern "C" void kernel_launch(void* const* d_in, const int* in_sizes, int n_in,
                              void* d_out, int out_size, void* d_ws, size_t ws_size,
                              hipStream_t stream) {
    const float* x = (const float*)d_in[0];
    const float* y = (const float*)d_in[1];
    (void)in_sizes; (void)n_in; (void)out_size; (void)d_ws; (void)ws_size;
    dtw_kernel<<<1, 256, 0, stream>>>(x, y, (float*)d_out);
}

// Round 3
// 236.174 us; speedup vs baseline: 2.0084x; 1.1629x over previous
//
#include <hip/hip_runtime.h>
#include <math.h>

// DTW 2048x2048, squared-diff cost, out = sqrt(DTW[2047][2047]).
//
// R=8 rows/lane, 4 waves (256 thr) on one CU, 1 wave/SIMD.
// Lane l of wave w owns rows 8*(64w+l) .. +7. At wave-local step tau, lane l
// computes column j = tau - l for its 8 rows (serial min3+fma chain).
// Lane-to-lane "up"/"diag": DPP wave_shr:1 of v[7]; lane 0 gets the ring
// value (row above the strip) injected via the DPP 'old' operand.
// Ring rows are unwrapped (2240 slots); ALL lanes store v[7]; lane 63
// writes each column last before the consumer's barrier epoch.
// Round-3 change: steady-state 64-step block = 8 chunks x 8 steps with
// double-buffered LDS prefetch (y + ring) so ds_read latency (~120cy) is
// hidden behind ~544cy of chunk compute instead of exposed every step.

#define NLEN  2048
#define NW    4
#define CSTEP 64
#define DSKEW 128
#define RROW  2240
#define GTOT  ((NW - 1) * DSKEW + NLEN + CSTEP)   // 2496
#define CH    8                                   // prefetch chunk (steps)
#define INFV  1e30f

__device__ __forceinline__ float dpp_shr1(float v, float inj) {
    int r = __builtin_amdgcn_update_dpp(
        __builtin_bit_cast(int, inj), __builtin_bit_cast(int, v),
        0x138 /*wave_shr:1*/, 0xF, 0xF, false /*bound_ctrl: keep old*/);
    return __builtin_bit_cast(float, r);
}

__global__ __launch_bounds__(256) void dtw_kernel(const float* __restrict__ X,
                                                  const float* __restrict__ Y,
                                                  float* __restrict__ out) {
    __shared__ __align__(16) float yS[NLEN];
    __shared__ float ring[(NW + 1) * RROW];   // row 0 = virtual row -1 (INF)

    const int tid  = threadIdx.x;
    const int w    = tid >> 6;
    const int lane = tid & 63;

    {
        const float4* Y4 = (const float4*)Y;
        float4* y4 = (float4*)yS;
        y4[tid]       = Y4[tid];
        y4[tid + 256] = Y4[tid + 256];
    }
    for (int k = tid; k < RROW; k += 256) ring[k] = INFV;
    __syncthreads();

    float xr[8];
    {
        const float4 xa = *(const float4*)&X[tid * 8];
        const float4 xb = *(const float4*)&X[tid * 8 + 4];
        xr[0] = xa.x; xr[1] = xa.y; xr[2] = xa.z; xr[3] = xa.w;
        xr[4] = xb.x; xr[5] = xb.y; xr[6] = xb.z; xr[7] = xb.w;
    }

    float v[8];
    #pragma unroll
    for (int r = 0; r < 8; ++r) v[r] = INFV;
    float uprev = (tid == 0) ? 0.0f : INFV;   // DTW[-1][-1]=0 seed (tid 0)

    const float* ringR = &ring[w * RROW + 64];
    float*       ringW = &ring[(w + 1) * RROW + 64];

    for (int gb = 0; gb < GTOT; gb += CSTEP) {
        const int tau0 = gb - w * DSKEW;

        if (tau0 >= CSTEP && tau0 + CSTEP <= NLEN) {
            // ---- steady state, software-pipelined LDS reads ----
            const float* yp = &yS[tau0 - lane];
            const float* rp = &ringR[tau0];
            float*       wp = &ringW[tau0 - lane];

            float yb[CH], ub[CH];
            #pragma unroll
            for (int k = 0; k < CH; ++k) { yb[k] = yp[k]; ub[k] = rp[k]; }

            #pragma unroll
            for (int c = 0; c < CSTEP / CH; ++c) {
                float yn[CH], un[CH];
                if (c + 1 < CSTEP / CH) {
                    #pragma unroll
                    for (int k = 0; k < CH; ++k) {
                        yn[k] = yp[(c + 1) * CH + k];
                        un[k] = rp[(c + 1) * CH + k];
                    }
                }
                #pragma unroll
                for (int s = 0; s < CH; ++s) {
                    float yj  = yb[s];
                    float u   = dpp_shr1(v[7], ub[s]);
                    float nv[8];
                    #pragma unroll
                    for (int r = 0; r < 8; ++r) {
                        float above = (r == 0) ? u : nv[r - 1];
                        float diag  = (r == 0) ? uprev : v[r - 1];
                        float m = fminf(fminf(v[r], diag), above);
                        float d = xr[r] - yj;
                        nv[r] = fmaf(d, d, m);
                    }
                    wp[c * CH + s] = nv[7];
                    uprev = u;
                    #pragma unroll
                    for (int r = 0; r < 8; ++r) v[r] = nv[r];
                }
                if (c + 1 < CSTEP / CH) {
                    #pragma unroll
                    for (int k = 0; k < CH; ++k) { yb[k] = yn[k]; ub[k] = un[k]; }
                }
            }
        } else if (tau0 >= 0 && tau0 < NLEN + CSTEP) {
            // ---- ramp up/down: per-lane activity guard ----
            for (int s = 0; s < CSTEP; ++s) {
                const int j = tau0 + s - lane;
                float u_r = ringR[tau0 + s];
                float yj  = yS[j & (NLEN - 1)];
                float u   = dpp_shr1(v[7], u_r);
                float nv[8];
                #pragma unroll
                for (int r = 0; r < 8; ++r) {
                    float above = (r == 0) ? u : nv[r - 1];
                    float diag  = (r == 0) ? uprev : v[r - 1];
                    float m = fminf(fminf(v[r], diag), above);
                    float d = xr[r] - yj;
                    nv[r] = fmaf(d, d, m);
                }
                if (j >= 0 && j < NLEN) {
                    ringW[j] = nv[7];
                    uprev = u;
                    #pragma unroll
                    for (int r = 0; r < 8; ++r) v[r] = nv[r];
                    if (w == NW - 1 && lane == 63 && j == NLEN - 1)
                        out[0] = sqrtf(nv[7]);
                }
            }
        }
        __syncthreads();
    }
}

extern "C" void kernel_launch(void* const* d_in, const int* in_sizes, int n_in,
                              void* d_out, int out_size, void* d_ws, size_t ws_size,
                              hipStream_t stream) {
    const float* x = (const float*)d_in[0];
    const float* y = (const float*)d_in[1];
    (void)in_sizes; (void)n_in; (void)out_size; (void)d_ws; (void)ws_size;
    dtw_kernel<<<1, 256, 0, stream>>>(x, y, (float*)d_out);
}